// Round 7
// baseline (449.312 us; speedup 1.0000x reference)
//
#include <hip/hip_runtime.h>

#define NUM_GRAPHS 1024
#define D 256

// ---------------------------------------------------------------------------
// init: zero the 1024 segment sums + 1024 counts each call.
// ---------------------------------------------------------------------------
__global__ void activs_init_kernel(float* __restrict__ sums, float* __restrict__ cnts) {
    int i = blockIdx.x * blockDim.x + threadIdx.x;
    if (i < NUM_GRAPHS) {
        sums[i] = 0.0f;
        cnts[i] = 0.0f;
    }
}

__device__ __forceinline__ float sq4(const float4 v) {
    return v.x * v.x + v.y * v.y + v.z * v.z + v.w * v.w;
}

// 4 rows per wave-iteration: 16 lanes own one row; lane l of group q loads
// float4s l, l+16, l+32, l+48 of row r0+q. 16 VGPRs per buffer.
struct R4 {
    float4 v0, v1, v2, v3;
};

__device__ __forceinline__ void load4(R4& R, const float* __restrict__ x,
                                      int r0, int q, int l) {
    const float4* src = (const float4*)(x + (size_t)(r0 + q) * D);
    R.v0 = src[l];
    R.v1 = src[l + 16];
    R.v2 = src[l + 32];
    R.v3 = src[l + 48];
}

__device__ __forceinline__ void store4(const R4& R, float* __restrict__ out,
                                       int r0, int q, int l) {
    float4* dst = (float4*)(out + (size_t)(r0 + q) * D);
    dst[l]      = R.v0;
    dst[l + 16] = R.v1;
    dst[l + 32] = R.v2;
    dst[l + 48] = R.v3;
}

// ---------------------------------------------------------------------------
// main: quarter-wave rows, 4 rows/iteration, software-pipelined DEPTH 2:
// while processing iteration i, the loads of i+1 AND i+2 are in flight
// (8 outstanding row-loads per wave in steady state; waits are vmcnt(8)-
// style on the oldest 4 only). 3 rotating register buffers; #pragma unroll 3
// lets the compiler rename the rotation away. batch is sorted; lane 0
// run-length-aggregates 4 consecutive rows, ~2 atomics per iteration.
// ---------------------------------------------------------------------------
__global__ __launch_bounds__(256) void activs_main_kernel(
        const float* __restrict__ x, const int* __restrict__ batch,
        float* __restrict__ out, float* __restrict__ sums,
        float* __restrict__ cnts, int N) {
    const int lane = threadIdx.x & 63;
    const int q = lane >> 4;          // 0..3: which row of the quad
    const int l = lane & 15;          // 0..15: float4 slot within the row
    const int waveId = (blockIdx.x * blockDim.x + threadIdx.x) >> 6;
    const int totalWaves = (gridDim.x * blockDim.x) >> 6;
    const int S = totalWaves * 4;     // row stride per iteration

    const int Nq = N & ~3;            // multiple-of-4 prefix (N=1e6 -> Nq==N)
    const int r0 = waveId * 4;

    // number of iterations for this wave
    const int k = (r0 < Nq) ? ((Nq - r0 - 4) / S + 1) : 0;

    if (k > 0) {
        R4 A, B, C;
        int4 wa, wb, wc;

        load4(A, x, r0, q, l);
        wa = *(const int4*)(batch + r0);
        if (k > 1) {
            load4(B, x, r0 + S, q, l);
            wb = *(const int4*)(batch + r0 + S);
        }

        int r = r0;
        #pragma unroll 3
        for (int i = 0; i < k; ++i) {
            if (i + 2 < k) {
                load4(C, x, r + 2 * S, q, l);      // depth-2 prefetch
                wc = *(const int4*)(batch + r + 2 * S);
            }

            store4(A, out, r, q, l);               // waits A's loads only

            float s = sq4(A.v0) + sq4(A.v1) + sq4(A.v2) + sq4(A.v3);
            #pragma unroll
            for (int m = 1; m <= 8; m <<= 1) s += __shfl_xor(s, m, 64);
            s = sqrtf(s);                          // group leaders hold norms

            const float n0 = __shfl(s, 0, 64);
            const float n1 = __shfl(s, 16, 64);
            const float n2 = __shfl(s, 32, 64);
            const float n3 = __shfl(s, 48, 64);

            if (lane == 0) {
                const float n[4] = {n0, n1, n2, n3};
                const int b[4] = {wa.x, wa.y, wa.z, wa.w};
                int seg = b[0];
                float rs = n[0], rc = 1.0f;
                #pragma unroll
                for (int t = 1; t < 4; ++t) {
                    if (b[t] == seg) { rs += n[t]; rc += 1.0f; }
                    else {
                        atomicAdd(&sums[seg], rs);
                        atomicAdd(&cnts[seg], rc);
                        seg = b[t]; rs = n[t]; rc = 1.0f;
                    }
                }
                atomicAdd(&sums[seg], rs);
                atomicAdd(&cnts[seg], rc);
            }

            A = B; wa = wb;
            B = C; wb = wc;
            r += S;
        }
    }

    // tail rows (only if N % 4 != 0; dead for N=1e6): wave 0, 64 lanes/row
    if (waveId == 0) {
        for (int t = Nq; t < N; ++t) {
            const float4 v = ((const float4*)(x + (size_t)t * D))[lane];
            ((float4*)(out + (size_t)t * D))[lane] = v;
            float s = sq4(v);
            #pragma unroll
            for (int m = 32; m; m >>= 1) s += __shfl_xor(s, m, 64);
            if (lane == 0) {
                atomicAdd(&sums[batch[t]], sqrtf(s));
                atomicAdd(&cnts[batch[t]], 1.0f);
            }
        }
    }
}

// ---------------------------------------------------------------------------
// finalize: per_graph = sum/count (0 where count==0); mask i < bmax;
// norm_mean = sum(per_graph * mask) / (bmax + 1). bmax = batch[N-1] (sorted).
// ---------------------------------------------------------------------------
__global__ __launch_bounds__(1024) void activs_finalize_kernel(
        const float* __restrict__ sums, const float* __restrict__ cnts,
        const int* __restrict__ batch, int N, float* __restrict__ out_scalar) {
    __shared__ float red[16];
    const int i = threadIdx.x;            // 0..1023 == graph id
    const int lane = i & 63;
    const int w = i >> 6;                 // 16 waves

    const float bmax = (float)batch[N - 1];

    float c = cnts[i];
    float pg = (c > 0.0f) ? (sums[i] / c) : 0.0f;
    float val = (((float)i) < bmax) ? pg : 0.0f;

    #pragma unroll
    for (int m = 32; m; m >>= 1) val += __shfl_xor(val, m, 64);
    if (lane == 0) red[w] = val;
    __syncthreads();

    if (w == 0) {
        float v = (lane < 16) ? red[lane] : 0.0f;
        #pragma unroll
        for (int m = 8; m; m >>= 1) v += __shfl_xor(v, m, 64);
        if (lane == 0) out_scalar[0] = v / (bmax + 1.0f);
    }
}

// ---------------------------------------------------------------------------
extern "C" void kernel_launch(void* const* d_in, const int* in_sizes, int n_in,
                              void* d_out, int out_size, void* d_ws, size_t ws_size,
                              hipStream_t stream) {
    const float* x = (const float*)d_in[0];
    const int* batch = (const int*)d_in[1];
    float* out = (float*)d_out;

    const int N = in_sizes[1];                 // 1,000,000 rows (D = 256)

    float* sums = (float*)d_ws;                // [1024]
    float* cnts = sums + NUM_GRAPHS;           // [1024]

    hipLaunchKernelGGL(activs_init_kernel, dim3(4), dim3(256), 0, stream, sums, cnts);

    hipLaunchKernelGGL(activs_main_kernel, dim3(2048), dim3(256), 0, stream,
                       x, batch, out, sums, cnts, N);

    hipLaunchKernelGGL(activs_finalize_kernel, dim3(1), dim3(1024), 0, stream,
                       sums, cnts, batch, N, out + (size_t)N * D);
}

// Round 8
// 404.449 us; speedup vs baseline: 1.1109x; 1.1109x over previous
//
#include <hip/hip_runtime.h>

#define NUM_GRAPHS 1024
#define D 256

// ---------------------------------------------------------------------------
// init: zero the 1024 segment sums + 1024 counts each call.
// ---------------------------------------------------------------------------
__global__ void activs_init_kernel(float* __restrict__ sums, float* __restrict__ cnts) {
    int i = blockIdx.x * blockDim.x + threadIdx.x;
    if (i < NUM_GRAPHS) {
        sums[i] = 0.0f;
        cnts[i] = 0.0f;
    }
}

__device__ __forceinline__ float sq4(const float4 v) {
    return v.x * v.x + v.y * v.y + v.z * v.z + v.w * v.w;
}

struct Rows {
    float4 a0, a1, a2, a3;   // row r0+q
    float4 b0, b1, b2, b3;   // row r0+4+q
};

__device__ __forceinline__ void load_rows(Rows& R, const float* __restrict__ x,
                                          int r0, int q, int l) {
    const float4* srcA = (const float4*)(x + (size_t)(r0 + q) * D);
    const float4* srcB = (const float4*)(x + (size_t)(r0 + 4 + q) * D);
    R.a0 = srcA[l];
    R.a1 = srcA[l + 16];
    R.a2 = srcA[l + 32];
    R.a3 = srcA[l + 48];
    R.b0 = srcB[l];
    R.b1 = srcB[l + 16];
    R.b2 = srcB[l + 32];
    R.b3 = srcB[l + 48];
}

__device__ __forceinline__ void store_rows(const Rows& R, float* __restrict__ out,
                                           int r0, int q, int l) {
    float4* dstA = (float4*)(out + (size_t)(r0 + q) * D);
    float4* dstB = (float4*)(out + (size_t)(r0 + 4 + q) * D);
    dstA[l]      = R.a0;
    dstA[l + 16] = R.a1;
    dstA[l + 32] = R.a2;
    dstA[l + 48] = R.a3;
    dstB[l]      = R.b0;
    dstB[l + 16] = R.b1;
    dstB[l + 32] = R.b2;
    dstB[l + 48] = R.b3;
}

// ---------------------------------------------------------------------------
// PHASE B: pure streaming. R6 structure (quarter-wave rows, 8 rows/iter,
// depth-1 prefetch) with ALL reduction machinery removed: no batch loads,
// no lane-0 serial section, no atomics. Group leaders (l==0) write the two
// row norms to norms[] (4B scatter, 4 active lanes). This is structurally
// a copy kernel + per-lane FMA + 4-step shuffle.
// ---------------------------------------------------------------------------
__global__ __launch_bounds__(256) void activs_stream_kernel(
        const float* __restrict__ x, float* __restrict__ out,
        float* __restrict__ norms, int N) {
    const int lane = threadIdx.x & 63;
    const int q = lane >> 4;          // 0..3: which row of the quad
    const int l = lane & 15;          // 0..15: float4 slot within the row
    const int waveId = (blockIdx.x * blockDim.x + threadIdx.x) >> 6;
    const int totalWaves = (gridDim.x * blockDim.x) >> 6;
    const int stride = totalWaves * 8;

    const int Nq = N & ~7;            // multiple-of-8 prefix (N=1e6 -> Nq==N)

    int r = waveId * 8;
    if (r < Nq) {
        Rows cur;
        load_rows(cur, x, r, q, l);

        while (true) {
            const int rn = r + stride;
            const bool more = (rn < Nq);
            Rows nxt;
            if (more) load_rows(nxt, x, rn, q, l);   // prefetch stays in flight

            store_rows(cur, out, r, q, l);           // waits cur loads only

            float sA = sq4(cur.a0) + sq4(cur.a1) + sq4(cur.a2) + sq4(cur.a3);
            float sB = sq4(cur.b0) + sq4(cur.b1) + sq4(cur.b2) + sq4(cur.b3);
            #pragma unroll
            for (int m = 1; m <= 8; m <<= 1) {
                sA += __shfl_xor(sA, m, 64);
                sB += __shfl_xor(sB, m, 64);
            }
            if (l == 0) {                            // lanes 0,16,32,48
                norms[r + q] = sqrtf(sA);
                norms[r + 4 + q] = sqrtf(sB);
            }

            if (!more) break;
            cur = nxt;
            r = rn;
        }
    }

    // tail rows (only if N % 8 != 0; dead for N=1e6)
    if (waveId == 0) {
        for (int t = Nq; t < N; ++t) {
            const float4 v = ((const float4*)(x + (size_t)t * D))[lane];
            ((float4*)(out + (size_t)t * D))[lane] = v;
            float s = sq4(v);
            #pragma unroll
            for (int m = 32; m; m >>= 1) s += __shfl_xor(s, m, 64);
            if (lane == 0) norms[t] = sqrtf(s);
        }
    }
}

// ---------------------------------------------------------------------------
// PHASE C: segment reduce. Each block owns 1024 consecutive rows; each
// thread run-length-reduces 4 consecutive rows (batch sorted) into LDS
// bins; block flushes non-empty bins with global atomics (~2 pairs/block).
// Traffic: 8MB coalesced reads.
// ---------------------------------------------------------------------------
__global__ __launch_bounds__(256) void activs_segred_kernel(
        const float* __restrict__ norms, const int* __restrict__ batch,
        float* __restrict__ sums, float* __restrict__ cnts, int N) {
    __shared__ float lsum[NUM_GRAPHS];
    __shared__ float lcnt[NUM_GRAPHS];
    const int tid = threadIdx.x;

    #pragma unroll
    for (int i = tid; i < NUM_GRAPHS; i += 256) {
        lsum[i] = 0.0f;
        lcnt[i] = 0.0f;
    }
    __syncthreads();

    const int base = blockIdx.x * 1024 + tid * 4;
    if (base < N) {
        // N is a multiple of 4, so base+3 < N whenever base < N
        const float4 nv = *(const float4*)(norms + base);
        const int4 bv = *(const int4*)(batch + base);
        const float n[4] = {nv.x, nv.y, nv.z, nv.w};
        const int b[4] = {bv.x, bv.y, bv.z, bv.w};
        int seg = b[0];
        float rs = n[0], rc = 1.0f;
        #pragma unroll
        for (int k = 1; k < 4; ++k) {
            if (b[k] == seg) { rs += n[k]; rc += 1.0f; }
            else {
                atomicAdd(&lsum[seg], rs);
                atomicAdd(&lcnt[seg], rc);
                seg = b[k]; rs = n[k]; rc = 1.0f;
            }
        }
        atomicAdd(&lsum[seg], rs);
        atomicAdd(&lcnt[seg], rc);
    }
    __syncthreads();

    #pragma unroll
    for (int i = tid; i < NUM_GRAPHS; i += 256) {
        if (lcnt[i] != 0.0f) {
            atomicAdd(&sums[i], lsum[i]);
            atomicAdd(&cnts[i], lcnt[i]);
        }
    }
}

// ---------------------------------------------------------------------------
// FALLBACK main (R6): fused streaming + segment atomics, used only if ws is
// too small for the norms buffer.
// ---------------------------------------------------------------------------
__global__ __launch_bounds__(256) void activs_fused_kernel(
        const float* __restrict__ x, const int* __restrict__ batch,
        float* __restrict__ out, float* __restrict__ sums,
        float* __restrict__ cnts, int N) {
    const int lane = threadIdx.x & 63;
    const int q = lane >> 4;
    const int l = lane & 15;
    const int waveId = (blockIdx.x * blockDim.x + threadIdx.x) >> 6;
    const int totalWaves = (gridDim.x * blockDim.x) >> 6;
    const int stride = totalWaves * 8;
    const int Nq = N & ~7;

    int r = waveId * 8;
    if (r < Nq) {
        Rows cur;
        load_rows(cur, x, r, q, l);
        int4 w0 = ((const int4*)(batch + r))[0];
        int4 w1 = ((const int4*)(batch + r))[1];

        while (true) {
            const int rn = r + stride;
            const bool more = (rn < Nq);
            Rows nxt;
            int4 nw0, nw1;
            if (more) {
                load_rows(nxt, x, rn, q, l);
                nw0 = ((const int4*)(batch + rn))[0];
                nw1 = ((const int4*)(batch + rn))[1];
            }
            store_rows(cur, out, r, q, l);

            float sA = sq4(cur.a0) + sq4(cur.a1) + sq4(cur.a2) + sq4(cur.a3);
            float sB = sq4(cur.b0) + sq4(cur.b1) + sq4(cur.b2) + sq4(cur.b3);
            #pragma unroll
            for (int m = 1; m <= 8; m <<= 1) {
                sA += __shfl_xor(sA, m, 64);
                sB += __shfl_xor(sB, m, 64);
            }
            sA = sqrtf(sA);
            sB = sqrtf(sB);
            const float n0 = __shfl(sA, 0, 64), n1 = __shfl(sA, 16, 64);
            const float n2 = __shfl(sA, 32, 64), n3 = __shfl(sA, 48, 64);
            const float n4 = __shfl(sB, 0, 64), n5 = __shfl(sB, 16, 64);
            const float n6 = __shfl(sB, 32, 64), n7 = __shfl(sB, 48, 64);

            if (lane == 0) {
                const float n[8] = {n0, n1, n2, n3, n4, n5, n6, n7};
                const int b[8] = {w0.x, w0.y, w0.z, w0.w, w1.x, w1.y, w1.z, w1.w};
                int seg = b[0];
                float rs = n[0], rc = 1.0f;
                #pragma unroll
                for (int k = 1; k < 8; ++k) {
                    if (b[k] == seg) { rs += n[k]; rc += 1.0f; }
                    else {
                        atomicAdd(&sums[seg], rs);
                        atomicAdd(&cnts[seg], rc);
                        seg = b[k]; rs = n[k]; rc = 1.0f;
                    }
                }
                atomicAdd(&sums[seg], rs);
                atomicAdd(&cnts[seg], rc);
            }

            if (!more) break;
            cur = nxt; w0 = nw0; w1 = nw1; r = rn;
        }
    }
    if (waveId == 0) {
        for (int t = Nq; t < N; ++t) {
            const float4 v = ((const float4*)(x + (size_t)t * D))[lane];
            ((float4*)(out + (size_t)t * D))[lane] = v;
            float s = sq4(v);
            #pragma unroll
            for (int m = 32; m; m >>= 1) s += __shfl_xor(s, m, 64);
            if (lane == 0) {
                atomicAdd(&sums[batch[t]], sqrtf(s));
                atomicAdd(&cnts[batch[t]], 1.0f);
            }
        }
    }
}

// ---------------------------------------------------------------------------
// finalize: per_graph = sum/count; mask i < bmax; mean / (bmax + 1).
// ---------------------------------------------------------------------------
__global__ __launch_bounds__(1024) void activs_finalize_kernel(
        const float* __restrict__ sums, const float* __restrict__ cnts,
        const int* __restrict__ batch, int N, float* __restrict__ out_scalar) {
    __shared__ float red[16];
    const int i = threadIdx.x;
    const int lane = i & 63;
    const int w = i >> 6;

    const float bmax = (float)batch[N - 1];

    float c = cnts[i];
    float pg = (c > 0.0f) ? (sums[i] / c) : 0.0f;
    float val = (((float)i) < bmax) ? pg : 0.0f;

    #pragma unroll
    for (int m = 32; m; m >>= 1) val += __shfl_xor(val, m, 64);
    if (lane == 0) red[w] = val;
    __syncthreads();

    if (w == 0) {
        float v = (lane < 16) ? red[lane] : 0.0f;
        #pragma unroll
        for (int m = 8; m; m >>= 1) v += __shfl_xor(v, m, 64);
        if (lane == 0) out_scalar[0] = v / (bmax + 1.0f);
    }
}

// ---------------------------------------------------------------------------
extern "C" void kernel_launch(void* const* d_in, const int* in_sizes, int n_in,
                              void* d_out, int out_size, void* d_ws, size_t ws_size,
                              hipStream_t stream) {
    const float* x = (const float*)d_in[0];
    const int* batch = (const int*)d_in[1];
    float* out = (float*)d_out;

    const int N = in_sizes[1];                 // 1,000,000 rows (D = 256)

    const size_t need = ((size_t)N + 2 * NUM_GRAPHS) * sizeof(float);
    if (ws_size >= need) {
        float* norms = (float*)d_ws;           // [N]
        float* sums = norms + N;               // [1024]
        float* cnts = sums + NUM_GRAPHS;       // [1024]

        hipLaunchKernelGGL(activs_init_kernel, dim3(4), dim3(256), 0, stream, sums, cnts);
        hipLaunchKernelGGL(activs_stream_kernel, dim3(2048), dim3(256), 0, stream,
                           x, out, norms, N);
        hipLaunchKernelGGL(activs_segred_kernel, dim3((N + 1023) / 1024), dim3(256),
                           0, stream, norms, batch, sums, cnts, N);
        hipLaunchKernelGGL(activs_finalize_kernel, dim3(1), dim3(1024), 0, stream,
                           sums, cnts, batch, N, out + (size_t)N * D);
    } else {
        float* sums = (float*)d_ws;            // [1024]
        float* cnts = sums + NUM_GRAPHS;       // [1024]

        hipLaunchKernelGGL(activs_init_kernel, dim3(4), dim3(256), 0, stream, sums, cnts);
        hipLaunchKernelGGL(activs_fused_kernel, dim3(2048), dim3(256), 0, stream,
                           x, batch, out, sums, cnts, N);
        hipLaunchKernelGGL(activs_finalize_kernel, dim3(1), dim3(1024), 0, stream,
                           sums, cnts, batch, N, out + (size_t)N * D);
    }
}